// Round 13
// baseline (214.556 us; speedup 1.0000x reference)
//
#include <hip/hip_runtime.h>
#include <cstdint>

typedef __bf16 bf16x8 __attribute__((ext_vector_type(8)));
typedef float  f32x4  __attribute__((ext_vector_type(4)));

// split 8 f32 into hi/lo bf16 fragments (hi+lo ~ 16-bit mantissa)
__device__ __forceinline__ void split8(const float* v, bf16x8& hi, bf16x8& lo) {
    union { bf16x8 v; __bf16 e[8]; } h, l;
    #pragma unroll
    for (int j = 0; j < 8; j++) {
        __bf16 hb = (__bf16)v[j];
        float  r  = v[j] - (float)hb;
        h.e[j] = hb; l.e[j] = (__bf16)r;
    }
    hi = h.v; lo = l.v;
}
__device__ __forceinline__ void splitstore(unsigned short* ph, unsigned short* pl, float v) {
    __bf16 hb = (__bf16)v;
    float  r  = v - (float)hb;
    __bf16 lb = (__bf16)r;
    unsigned short hu, lu;
    __builtin_memcpy(&hu, &hb, 2); __builtin_memcpy(&lu, &lb, 2);
    *ph = hu; *pl = lu;
}
__device__ __forceinline__ unsigned short f2bfh(float v) {
    __bf16 hb = (__bf16)v; unsigned short hu;
    __builtin_memcpy(&hu, &hb, 2); return hu;
}

// ---------------- Kzero: zero the atomic-accumulation region (fallback) -------
__global__ __launch_bounds__(256)
void kzero(float4* __restrict__ p) {
    p[blockIdx.x * 256 + threadIdx.x] = float4{0.f, 0.f, 0.f, 0.f};
}

// ---------------- Kpre: ballot bitpack (blocks 0..8191) + weight split --------
__global__ __launch_bounds__(256)
void kpre(const int* __restrict__ adj, unsigned long long* __restrict__ bm64,
          const float* __restrict__ w1, const float* __restrict__ w2,
          unsigned short* __restrict__ w1h, unsigned short* __restrict__ w1l,
          unsigned short* __restrict__ w2h, unsigned short* __restrict__ w2l) {
    int bx = blockIdx.x, tid = threadIdx.x;
    if (bx < 8192) {
        int row = bx >> 1, jbase = (bx & 1) * 2048;
        int wave = tid >> 6, lane = tid & 63;
        const int* base = adj + (size_t)row * 4096 + jbase + wave * 512;
        unsigned long long* bmw = bm64 + row * 64 + (jbase >> 6) + wave * 8;
        #pragma unroll
        for (int it = 0; it < 8; it++) {
            int v = base[it * 64 + lane];
            unsigned long long mask = __ballot(v != 0);
            if (lane == 0) bmw[it] = mask;
        }
        return;
    }
    int e = ((bx - 8192) * 256 + tid) * 4;
    const float* src; unsigned short *dh, *dl;
    if (e < 65536) { src = w1 + e; dh = w1h + e; dl = w1l + e; }
    else { int e2 = e - 65536; src = w2 + e2; dh = w2h + e2; dl = w2l + e2; }
    #pragma unroll
    for (int j = 0; j < 4; j++) splitstore(dh + j, dl + j, src[j]);
}

// ---------------- K1: H1T bf16-hi + rank-1 attention vectors epilogue ---------
// Per row i, head h: f1,f2 reduced; store f2 (f32), -f1, exp(f1), exp(.01f1)
// (f32) and bf16(exp(f2)), bf16(exp(.01f2)) -- the attention inner loop then
// needs NO transcendentals.
__global__ __launch_bounds__(256)
void k1_gemm(const float* __restrict__ x,
             const unsigned short* __restrict__ w1h,
             const unsigned short* __restrict__ w1l,
             const float* __restrict__ a11, const float* __restrict__ a21,
             unsigned short* __restrict__ h1t_hi,
             float* __restrict__ f2f, float* __restrict__ nf,
             float* __restrict__ ue, float* __restrict__ ae,
             unsigned short* __restrict__ vb, unsigned short* __restrict__ bb) {
    int tid = threadIdx.x, wave = tid >> 6, lane = tid & 63;
    int q = lane >> 4, m = lane & 15;
    int i0 = blockIdx.x * 16;
    int c0 = wave * 64;                     // wave == head
    f32x4 acc[4] = {};
    #pragma unroll
    for (int k0 = 0; k0 < 256; k0 += 32) {
        bf16x8 ah, al;
        split8(x + (i0 + m) * 256 + k0 + q * 8, ah, al);
        #pragma unroll
        for (int ct = 0; ct < 4; ct++) {
            bf16x8 bh = *(const bf16x8*)(w1h + (c0 + ct * 16 + m) * 256 + k0 + q * 8);
            bf16x8 bl = *(const bf16x8*)(w1l + (c0 + ct * 16 + m) * 256 + k0 + q * 8);
            acc[ct] = __builtin_amdgcn_mfma_f32_16x16x32_bf16(ah, bh, acc[ct], 0, 0, 0);
            acc[ct] = __builtin_amdgcn_mfma_f32_16x16x32_bf16(al, bh, acc[ct], 0, 0, 0);
            acc[ct] = __builtin_amdgcn_mfma_f32_16x16x32_bf16(ah, bl, acc[ct], 0, 0, 0);
        }
    }
    float a1v[4], a2v[4];
    #pragma unroll
    for (int ct = 0; ct < 4; ct++) {
        a1v[ct] = a11[wave * 64 + ct * 16 + m];
        a2v[ct] = a21[wave * 64 + ct * 16 + m];
    }
    #pragma unroll
    for (int r = 0; r < 4; r++) {
        int i = i0 + q * 4 + r;
        float s1 = 0.f, s2 = 0.f;
        #pragma unroll
        for (int ct = 0; ct < 4; ct++) {
            int c = c0 + ct * 16 + m;
            h1t_hi[c * 4096 + i] = f2bfh(acc[ct][r]);
            s1 += acc[ct][r] * a1v[ct];
            s2 += acc[ct][r] * a2v[ct];
        }
        #pragma unroll
        for (int off = 1; off < 16; off <<= 1) {
            s1 += __shfl_xor(s1, off);
            s2 += __shfl_xor(s2, off);
        }
        if (m == 0) {
            int idx = wave * 4096 + i;
            f2f[idx] = s2;
            nf[idx]  = -s1;
            ue[idx]  = __expf(s1);
            ae[idx]  = __expf(0.01f * s1);
            vb[idx]  = f2bfh(__expf(s2));
            bb[idx]  = f2bfh(__expf(0.01f * s2));
        }
    }
}

// ---------------- attention (128-row tiles, rank-1 P, dual MFMA accum) --------
// p_ij = adj * [s!=0] * (s>0 ? u_i v_j : a_i b_j), s = f1_i + f2_j.
// Inner loop: 1 cmp + 1 neq + bit test + 2 cndmask per element -- no exp/cvt.
// acc1 = sum sigma*v_j*H, acc2 = sum (1-sigma)*b_j*H; epilogue u_i*acc1+a_i*acc2.
// z via ones-column MFMA on the same bf16 A fragments (self-consistent).
template<int NCT, int JLEN, bool ATOM>
__global__ __launch_bounds__(256)
void attn_kernel(const unsigned char* __restrict__ bmb,
                 const float* __restrict__ f2f_all,
                 const float* __restrict__ nf_all,
                 const float* __restrict__ ue_all,
                 const float* __restrict__ ae_all,
                 const unsigned short* __restrict__ vb_all,
                 const unsigned short* __restrict__ bb_all,
                 const unsigned short* __restrict__ BTh_all,
                 float* __restrict__ pacc,
                 float* __restrict__ zacc,
                 int pstride) {
    constexpr int S    = JLEN / 32;
    constexpr int ST   = (S % 8 == 0) ? S + 4 : S;
    constexpr int PR   = S / 4;
    constexpr int NU4  = 128 * PR;
    constexpr int CR   = NCT * 16;
    constexpr int TSTR = 40;
    int tid = threadIdx.x, wave = tid >> 6, lane = tid & 63;
    int q = lane >> 4, m = lane & 15;
    int head = blockIdx.y;
    int i0 = blockIdx.x * 128;
    int jstart = blockIdx.z * JLEN;

    if (!ATOM) {
        pacc += (size_t)blockIdx.z * (size_t)(4096 * pstride);
        zacc += (size_t)blockIdx.z * (size_t)((NCT == 4 ? 4 : 1) * 4096);
    }

    __shared__ unsigned int ldsbm[128 * ST];
    __shared__ unsigned short ldsbt[2][CR * TSTR];

    const unsigned short* BTh = BTh_all + (size_t)head * CR * 4096;

    for (int c = tid; c < NU4; c += 256) {
        int row = c / PR, part = c % PR;
        uint4 v = *(const uint4*)(bmb + (size_t)(i0 + row) * 512 + (jstart >> 3) + part * 16);
        *(uint4*)&ldsbm[row * ST + part * 4] = v;
    }
    uint4 vstage;
    int sc = tid >> 2, sp = tid & 3;
    if (tid < CR * 4) {
        vstage = *(const uint4*)(BTh + (size_t)sc * 4096 + jstart + sp * 8);
        *(uint4*)&ldsbt[0][sc * TSTR + sp * 8] = vstage;
    }

    const float* f2f = f2f_all + head * 4096;
    const unsigned short* vb = vb_all + head * 4096;
    const unsigned short* bb = bb_all + head * 4096;
    int col0 = head * CR;

    int r0 = wave * 32;
    float nfa = nf_all[head * 4096 + i0 + r0 + m];
    float nfb = nf_all[head * 4096 + i0 + r0 + 16 + m];

    // ones-column B fragment: B[k][0]=1 -> lanes with (lane&15)==0 hold 1.0
    bf16x8 bones;
    {
        union { bf16x8 v; unsigned short u[8]; } t;
        unsigned short one = (m == 0) ? 0x3F80 : 0;
        #pragma unroll
        for (int j = 0; j < 8; j++) t.u[j] = one;
        bones = t.v;
    }

    f32x4 acc1a[NCT] = {}, acc2a[NCT] = {}, acc1b[NCT] = {}, acc2b[NCT] = {};
    f32x4 z1a = {}, z2a = {}, z1b = {}, z2b = {};

    constexpr int NIT = JLEN / 32;
    for (int it = 0; it < NIT; it++) {
        __syncthreads();
        int jl = it * 32;
        if (it + 1 < NIT && tid < CR * 4)
            vstage = *(const uint4*)(BTh + (size_t)sc * 4096 + jstart + jl + 32 + sp * 8);

        unsigned int md0 = ldsbm[(r0 + m) * ST + (jl >> 5)];
        unsigned int md1 = ldsbm[(r0 + 16 + m) * ST + (jl >> 5)];
        const float4* f2p = (const float4*)(f2f + jstart + jl + q * 8);
        float4 fa = f2p[0], fb = f2p[1];
        float fv[8] = {fa.x, fa.y, fa.z, fa.w, fb.x, fb.y, fb.z, fb.w};
        union { bf16x8 v; unsigned short u[8]; } vbu, bbu, A1a, A2a, A1b, A2b;
        vbu.v = *(const bf16x8*)(vb + jstart + jl + q * 8);
        bbu.v = *(const bf16x8*)(bb + jstart + jl + q * 8);
        #pragma unroll
        for (int jj = 0; jj < 8; jj++) {
            int bit = q * 8 + jj;
            float f = fv[jj];
            bool nz0 = ((md0 >> bit) & 1u) && (f != nfa);
            bool nz1 = ((md1 >> bit) & 1u) && (f != nfb);
            bool p0 = f > nfa;
            bool p1 = f > nfb;
            A1a.u[jj] = (nz0 && p0)  ? vbu.u[jj] : (unsigned short)0;
            A2a.u[jj] = (nz0 && !p0) ? bbu.u[jj] : (unsigned short)0;
            A1b.u[jj] = (nz1 && p1)  ? vbu.u[jj] : (unsigned short)0;
            A2b.u[jj] = (nz1 && !p1) ? bbu.u[jj] : (unsigned short)0;
        }
        int cur = it & 1;
        #pragma unroll
        for (int ct = 0; ct < NCT; ct++) {
            bf16x8 bh = *(const bf16x8*)&ldsbt[cur][(ct * 16 + m) * TSTR + q * 8];
            acc1a[ct] = __builtin_amdgcn_mfma_f32_16x16x32_bf16(A1a.v, bh, acc1a[ct], 0, 0, 0);
            acc2a[ct] = __builtin_amdgcn_mfma_f32_16x16x32_bf16(A2a.v, bh, acc2a[ct], 0, 0, 0);
            acc1b[ct] = __builtin_amdgcn_mfma_f32_16x16x32_bf16(A1b.v, bh, acc1b[ct], 0, 0, 0);
            acc2b[ct] = __builtin_amdgcn_mfma_f32_16x16x32_bf16(A2b.v, bh, acc2b[ct], 0, 0, 0);
        }
        z1a = __builtin_amdgcn_mfma_f32_16x16x32_bf16(A1a.v, bones, z1a, 0, 0, 0);
        z2a = __builtin_amdgcn_mfma_f32_16x16x32_bf16(A2a.v, bones, z2a, 0, 0, 0);
        z1b = __builtin_amdgcn_mfma_f32_16x16x32_bf16(A1b.v, bones, z1b, 0, 0, 0);
        z2b = __builtin_amdgcn_mfma_f32_16x16x32_bf16(A2b.v, bones, z2b, 0, 0, 0);
        if (it + 1 < NIT && tid < CR * 4)
            *(uint4*)&ldsbt[1 - cur][sc * TSTR + sp * 8] = vstage;
    }
    // epilogue: val = u_i*acc1 + a_i*acc2; z = u_i*z1 + a_i*z2 (col0 lanes)
    #pragma unroll
    for (int r = 0; r < 4; r++) {
        int rowA = i0 + r0 + q * 4 + r;
        int rowB = rowA + 16;
        float uA = ue_all[head * 4096 + rowA], aA = ae_all[head * 4096 + rowA];
        float uB = ue_all[head * 4096 + rowB], aB = ae_all[head * 4096 + rowB];
        if (m == 0) {
            float za = uA * z1a[r] + aA * z2a[r];
            float zb = uB * z1b[r] + aB * z2b[r];
            if (ATOM) {
                atomicAdd(&zacc[head * 4096 + rowA], za);
                atomicAdd(&zacc[head * 4096 + rowB], zb);
            } else {
                zacc[head * 4096 + rowA] = za;
                zacc[head * 4096 + rowB] = zb;
            }
        }
        #pragma unroll
        for (int ct = 0; ct < NCT; ct++) {
            int col = col0 + ct * 16 + m;
            float vA = uA * acc1a[ct][r] + aA * acc2a[ct][r];
            float vB = uB * acc1b[ct][r] + aB * acc2b[ct][r];
            if (ATOM) {
                atomicAdd(&pacc[rowA * pstride + col], vA);
                atomicAdd(&pacc[rowB * pstride + col], vB);
            } else {
                pacc[rowA * pstride + col] = vA;
                pacc[rowB * pstride + col] = vB;
            }
        }
    }
}

// ---------------- Fin1c: helu = elu(sum p1 / sum z1), coalesced, hi/lo bf16 ---
__global__ __launch_bounds__(256)
void fin1c(const float* __restrict__ pp, const float* __restrict__ zp, int nj,
           unsigned short* __restrict__ hh, unsigned short* __restrict__ hl) {
    int row = blockIdx.x, col = threadIdx.x;
    float s = 0.f;
    for (int jc = 0; jc < nj; jc++) s += pp[(size_t)jc * (4096 * 256) + row * 256 + col];
    int head = col >> 6;
    float zz = 0.f;
    for (int jc = 0; jc < nj; jc++) zz += zp[jc * (4 * 4096) + head * 4096 + row];
    float v = s / zz;
    v = (v > 0.f) ? v : (__expf(v) - 1.0f);
    splitstore(&hh[row * 256 + col], &hl[row * 256 + col], v);
}

// ---------------- K3: h2 = h_elu @ W2^T (hi/lo), layer-2 vectors epilogue -----
__global__ __launch_bounds__(256)
void k3_layer2(const unsigned short* __restrict__ helu_hi,
               const unsigned short* __restrict__ helu_lo,
               const unsigned short* __restrict__ w2h,
               const unsigned short* __restrict__ w2l,
               const float* __restrict__ a12,
               const float* __restrict__ a22,
               unsigned short* __restrict__ h2t_hi,
               float* __restrict__ f2f, float* __restrict__ nf,
               float* __restrict__ ue, float* __restrict__ ae,
               unsigned short* __restrict__ vb, unsigned short* __restrict__ bb) {
    int tid = threadIdx.x, wave = tid >> 6, lane = tid & 63;
    int q = lane >> 4, m = lane & 15;
    int i0 = (blockIdx.x * 4 + wave) * 16;
    f32x4 acc = {};
    #pragma unroll
    for (int k0 = 0; k0 < 256; k0 += 32) {
        bf16x8 ah = *(const bf16x8*)(helu_hi + (i0 + m) * 256 + k0 + q * 8);
        bf16x8 al = *(const bf16x8*)(helu_lo + (i0 + m) * 256 + k0 + q * 8);
        bf16x8 bh = *(const bf16x8*)(w2h + m * 256 + k0 + q * 8);
        bf16x8 bl = *(const bf16x8*)(w2l + m * 256 + k0 + q * 8);
        acc = __builtin_amdgcn_mfma_f32_16x16x32_bf16(ah, bh, acc, 0, 0, 0);
        acc = __builtin_amdgcn_mfma_f32_16x16x32_bf16(al, bh, acc, 0, 0, 0);
        acc = __builtin_amdgcn_mfma_f32_16x16x32_bf16(ah, bl, acc, 0, 0, 0);
    }
    float a1v = a12[m], a2v = a22[m];
    #pragma unroll
    for (int r = 0; r < 4; r++) {
        float v = acc[r];
        int i = i0 + q * 4 + r;
        h2t_hi[m * 4096 + i] = f2bfh(v);
        float s1 = v * a1v, s2 = v * a2v;
        #pragma unroll
        for (int off = 1; off < 16; off <<= 1) {
            s1 += __shfl_xor(s1, off);
            s2 += __shfl_xor(s2, off);
        }
        if (m == 0) {
            f2f[i] = s2;
            nf[i]  = -s1;
            ue[i]  = __expf(s1);
            ae[i]  = __expf(0.01f * s1);
            vb[i]  = f2bfh(__expf(s2));
            bb[i]  = f2bfh(__expf(0.01f * s2));
        }
    }
}

// ---------------- Fin2: out = sum(p2)/sum(z2) (f32) ---------------------------
__global__ __launch_bounds__(256)
void fin2(const float* __restrict__ pp, const float* __restrict__ zp, int nj,
          float* __restrict__ out) {
    int idx = blockIdx.x * 256 + threadIdx.x;      // 65536
    float s = 0.f;
    for (int jc = 0; jc < nj; jc++) s += pp[jc * 65536 + idx];
    float zz = 0.f;
    for (int jc = 0; jc < nj; jc++) zz += zp[jc * 4096 + (idx >> 4)];
    out[idx] = s / zz;
}

extern "C" void kernel_launch(void* const* d_in, const int* in_sizes, int n_in,
                              void* d_out, int out_size, void* d_ws, size_t ws_size,
                              hipStream_t stream) {
    const float* x   = (const float*)d_in[0];
    const int*   adj = (const int*)d_in[1];
    const float* w1  = (const float*)d_in[2];
    const float* a11 = (const float*)d_in[3];
    const float* a21 = (const float*)d_in[4];
    const float* w2  = (const float*)d_in[5];
    const float* a12 = (const float*)d_in[6];
    const float* a22 = (const float*)d_in[7];
    float* out = (float*)d_out;

    uint8_t* w = (uint8_t*)d_ws;
    unsigned long long* bm  = (unsigned long long*)(w);                       // 2 MB
    unsigned short* h1t_hi  = (unsigned short*)(w + (2u << 20));              // 2 MB
    unsigned short* h2t_hi  = (unsigned short*)(w + (4u << 20));              // 128 KB
    unsigned short* w1h     = (unsigned short*)(w + (4u << 20) + (128u << 10)); // 128 KB
    unsigned short* w1l     = (unsigned short*)(w + (4u << 20) + (256u << 10)); // 128 KB
    unsigned short* w2h     = (unsigned short*)(w + (4u << 20) + (384u << 10)); // 8 KB
    unsigned short* w2l     = (unsigned short*)(w + (4u << 20) + (392u << 10)); // 8 KB
    // layer-1 rank-1 vectors
    float*          f2f1    = (float*)(w + (4u << 20) + (400u << 10));        // 64 KB
    float*          nf1a    = (float*)(w + (4u << 20) + (464u << 10));        // 64 KB
    float*          ue1     = (float*)(w + (4u << 20) + (528u << 10));        // 64 KB
    float*          ae1     = (float*)(w + (4u << 20) + (592u << 10));        // 64 KB
    unsigned short* vb1     = (unsigned short*)(w + (4u << 20) + (656u << 10)); // 32 KB
    unsigned short* bb1     = (unsigned short*)(w + (4u << 20) + (688u << 10)); // 32 KB
    // layer-2 rank-1 vectors
    float*          f2f2    = (float*)(w + (4u << 20) + (720u << 10));        // 16 KB
    float*          nf2a    = (float*)(w + (4u << 20) + (736u << 10));        // 16 KB
    float*          ue2     = (float*)(w + (4u << 20) + (752u << 10));        // 16 KB
    float*          ae2     = (float*)(w + (4u << 20) + (768u << 10));        // 16 KB
    unsigned short* vb2     = (unsigned short*)(w + (4u << 20) + (784u << 10)); // 8 KB
    unsigned short* bb2     = (unsigned short*)(w + (4u << 20) + (792u << 10)); // 8 KB
    unsigned short* helu_hi = (unsigned short*)(w + (4u << 20) + (800u << 10)); // 2 MB
    unsigned short* helu_lo = (unsigned short*)(w + (4u << 20) + (2848u << 10)); // 2 MB

    bool big = ws_size >= ((size_t)48 << 20);
    float* p1 = (float*)(w + (9u << 20));
    float *z1, *p2, *z2;
    if (big) {
        z1 = p1 + (size_t)8 * 4096 * 256;       // p1: 8 x 4 MB = 32 MB
        p2 = z1 + 8 * 4 * 4096;                 // z1: 8 x 64 KB
        z2 = p2 + (size_t)16 * 4096 * 16;       // p2: 16 x 256 KB = 4 MB
    } else {
        z1 = p1 + 4096 * 256;                   // p1: 4 MB
        p2 = z1 + 4 * 4096;                     // z1: 64 KB
        z2 = p2 + 4096 * 16;                    // p2: 256 KB, z2: 16 KB
    }

    if (!big) kzero<<<1108, 256, 0, stream>>>((float4*)p1);
    kpre<<<8260, 256, 0, stream>>>(adj, bm, w1, w2, w1h, w1l, w2h, w2l);
    k1_gemm<<<256, 256, 0, stream>>>(x, w1h, w1l, a11, a21, h1t_hi,
                                     f2f1, nf1a, ue1, ae1, vb1, bb1);
    if (big)
        attn_kernel<4, 512, false><<<dim3(32, 4, 8), 256, 0, stream>>>(
            (const unsigned char*)bm, f2f1, nf1a, ue1, ae1, vb1, bb1,
            h1t_hi, p1, z1, 256);
    else
        attn_kernel<4, 512, true><<<dim3(32, 4, 8), 256, 0, stream>>>(
            (const unsigned char*)bm, f2f1, nf1a, ue1, ae1, vb1, bb1,
            h1t_hi, p1, z1, 256);
    fin1c<<<4096, 256, 0, stream>>>(p1, z1, big ? 8 : 1, helu_hi, helu_lo);
    k3_layer2<<<64, 256, 0, stream>>>(helu_hi, helu_lo, w2h, w2l, a12, a22,
                                      h2t_hi, f2f2, nf2a, ue2, ae2, vb2, bb2);
    if (big)
        attn_kernel<1, 256, false><<<dim3(32, 1, 16), 256, 0, stream>>>(
            (const unsigned char*)bm, f2f2, nf2a, ue2, ae2, vb2, bb2,
            h2t_hi, p2, z2, 16);
    else
        attn_kernel<1, 256, true><<<dim3(32, 1, 16), 256, 0, stream>>>(
            (const unsigned char*)bm, f2f2, nf2a, ue2, ae2, vb2, bb2,
            h2t_hi, p2, z2, 16);
    fin2<<<256, 256, 0, stream>>>(p2, z2, big ? 16 : 1, out);
}